// Round 2
// baseline (93.247 us; speedup 1.0000x reference)
//
#include <hip/hip_runtime.h>
#include <hip/hip_bf16.h>

// AEV for M=32 molecules, A=48 atoms, S=4 species.
// Output [M, A, 384]: [0:64] radial = species*16+shfR; [64:384] angular =
// pair_species_idx*32 + shfA*8 + shfZ.
//
// WAVE-INDEPENDENT version: 256 blocks x 384 threads (6 waves); wave w of
// block (m, q) owns center ci = q*6+w. ZERO __syncthreads: each wave loads
// coords into registers (redundant, L2-hit), builds its own cutoff-compacted
// lists via its own __ballot, and works entirely in a private LDS region.
// Intra-wave LDS RAW/WAR ordering via explicit s_waitcnt lgkmcnt(0) +
// sched_barrier(0) (wave-local, no cross-wave coupling).
//
// Angular: pairs staged in <=64-pair chunks (float4{cv,sv,pd,pe}); species-row
// rank/counts computed with 10 ballots (in-register counting sort: counts and
// starts are uniform SGPRs, no LDS bins/atomics/scan). Row-pair loop u=0..4:
// half-wave p0 processes row 2u+p0 (its natural output row), 2-address LDS
// broadcast, no shfl reconciliation. Radial folded single-exp2 per
// (neighbor, shell). Outputs stored directly per lane (no partial reduction).
//
// Dtype probed at runtime (ShfR[0] as f32 == 0.9 <=> f32 inputs).

#define NA 48
#define RCR_F 5.2f
#define RCA_F 3.5f
#define PI_F 3.14159265358979f
#define LOG2E_F 1.44269504088896f
#define RADLEN 64
#define AEVLEN 384
#define WPB 6   // waves (=centers) per block
#define BPM 8   // blocks per molecule (8*6 = 48 centers)

// Wave-local LDS drain: order prior ds_write/ds_read before subsequent ones.
// "memory" clobber blocks IR-level reordering; sched_barrier(0) blocks the
// backend scheduler from hoisting dependent ops above the wait (guide rule #18).
#define WAVE_SYNC() do { asm volatile("s_waitcnt lgkmcnt(0)" ::: "memory"); \
                         __builtin_amdgcn_sched_barrier(0); } while (0)

struct WaveMem {
    float ra[NA]; unsigned rbu[NA];                                // radial folded
    float ad[NA], avx[NA], avy[NA], avz[NA], afc[NA]; int asp[NA]; // d<=RCA list
    float4 pstage[64];   // staged pairs {cv, sv, pd, pe}
    int    sortidx[64];  // row-sorted pair indices (into pstage)
};

template <typename T> __device__ __forceinline__ float toF(const T* p, int i);
template <> __device__ __forceinline__ float toF<float>(const float* p, int i) { return p[i]; }
template <> __device__ __forceinline__ float toF<__hip_bfloat16>(const __hip_bfloat16* p, int i) { return __bfloat162float(p[i]); }

template <typename T> __device__ __forceinline__ void stF(T* p, size_t i, float v);
template <> __device__ __forceinline__ void stF<float>(float* p, size_t i, float v) { p[i] = v; }
template <> __device__ __forceinline__ void stF<__hip_bfloat16>(__hip_bfloat16* p, size_t i, float v) { p[i] = __float2bfloat16(v); }

__device__ __forceinline__ int triu_idx(int a, int b) {
    int lo = a < b ? a : b;
    int hi = a < b ? b : a;
    return lo * 4 - (lo * (lo - 1)) / 2 + (hi - lo);  // 4x4 upper-tri, 0..9
}

template <typename T>
__device__ void aev_body(WaveMem* wm,
    const T* __restrict__ coords, const T* __restrict__ etaR_p,
    const T* __restrict__ shfR_p, const T* __restrict__ etaA_p,
    const T* __restrict__ zeta_p, const T* __restrict__ shfA_p,
    const T* __restrict__ shfZ_p, const int* __restrict__ species,
    T* __restrict__ out)
{
    const int tid  = threadIdx.x;   // 0..383
    const int lane = tid & 63;
    const int w    = tid >> 6;      // wave id 0..5
    const int bid  = blockIdx.x;    // 0..255
    const int m    = bid >> 3;      // molecule
    const int ci   = (bid & 7) * WPB + w;  // this wave's center atom
    WaveMem& WV = wm[w];

    const float etaR = toF(etaR_p, 0);
    const float etaA = toF(etaA_p, 0);
    const float zeta = toF(zeta_p, 0);
    const float kR   = etaR * LOG2E_F;
    const float k2   = etaA * LOG2E_F;

    // ---- per-lane atom coords in registers (lane i <-> atom i) ----
    float ax = 0.f, ay = 0.f, az = 0.f; int aspec = 0;
    if (lane < NA) {
        int g = m * NA + lane;
        ax = toF(coords, 3 * g + 0);
        ay = toF(coords, 3 * g + 1);
        az = toF(coords, 3 * g + 2);
        aspec = species[g];
    }
    const float cx = __shfl(ax, ci);
    const float cy = __shfl(ay, ci);
    const float cz = __shfl(az, ci);

    // ---- neighbor build (whole wave) ----
    float dx = 0.f, dy = 0.f, dz = 0.f, d = 1e30f;
    if (lane < NA && lane != ci) {
        dx = ax - cx; dy = ay - cy; dz = az - cz;
        d = sqrtf(dx * dx + dy * dy + dz * dz);
    }
    const unsigned long long mR = __ballot(d <= RCR_F);
    const unsigned long long mA = __ballot(d <= RCA_F);
    const unsigned long long lanebit = 1ull << lane;
    const unsigned long long below = lanebit - 1ull;
    if (mR & lanebit) {
        int s = __popcll(mR & below);
        float fcR = 0.5f * __cosf(d * (PI_F / RCR_F)) + 0.5f;
        // 0.25*exp(-etaR*(d-s)^2)*fc = exp2(ra*s + rb - kR*s^2)
        float rb = fmaxf(__log2f(0.25f * fcR) - kR * d * d, -8.0e4f);
        WV.ra[s]  = 2.f * kR * d;
        WV.rbu[s] = (__float_as_uint(rb) & ~3u) | (unsigned)aspec;
    }
    if (mA & lanebit) {
        int s = __popcll(mA & below);
        WV.ad[s]  = d;
        WV.avx[s] = dx; WV.avy[s] = dy; WV.avz[s] = dz;
        WV.afc[s] = 0.5f * __cosf(d * (PI_F / RCA_F)) + 0.5f;
        WV.asp[s] = aspec;
    }
    const int nR  = (int)__popcll(mR);
    const int nAn = (int)__popcll(mA);
    WAVE_SYNC();   // lists visible to this wave's subsequent reads

    // ---- radial: lane = sp*16 + shfR_idx, serial over neighbors ----
    const float myShfR = toF(shfR_p, lane & 15);
    const int   mySp   = lane >> 4;
    const float myRc   = kR * myShfR * myShfR;
    float racc = 0.f;
    for (int i = 0; i < nR; ++i) {
        unsigned ru = WV.rbu[i];
        float arg = __builtin_fmaf(WV.ra[i], myShfR, __uint_as_float(ru)) - myRc;
        float t = __builtin_amdgcn_exp2f(arg);
        racc += ((int)(ru & 3u) == mySp) ? t : 0.f;
    }
    const size_t ob = (size_t)(m * NA + ci) * AEVLEN;
    stF(out, ob + lane, racc);   // fire-and-forget radial store

    // ---- angular ----
    const int myA = (lane >> 3) & 3;
    const int myZ = lane & 7;
    const int p0  = lane >> 5;    // half-wave: owns rows 2u+p0
    const float myShfA = toF(shfA_p, myA);
    const float myShfZ = toF(shfZ_p, myZ);
    const float myCz = __cosf(myShfZ);
    const float mySz = __sinf(myShfZ);
    const float myLc = k2 * myShfA * myShfA;
    const bool  z32  = (zeta == 32.f);

    float accs[5] = {0.f, 0.f, 0.f, 0.f, 0.f};
    const int np = nAn * (nAn - 1) / 2;

    for (int c0 = 0; c0 < np; c0 += 64) {
        const int nc = (np - c0 < 64) ? (np - c0) : 64;
        const bool active = lane < nc;
        int myrow = -1;
        if (active) {
            int p = c0 + lane;
            // decode p -> (j,k), j<k: T(j) = j*(b-j)/2, b = 2n-1
            const int b = 2 * nAn - 1;
            float sq = sqrtf((float)(b * b - 8 * p));
            int j = (int)(((float)b - sq) * 0.5f);
            if ((j + 1) * (b - 1 - j) <= 2 * p) j++;
            if (j * (b - j) > 2 * p) j--;
            int k = p - ((j * (b - j)) >> 1) + j + 1;

            float d1 = WV.ad[j], d2 = WV.ad[k];
            float dot = WV.avx[j] * WV.avx[k] + WV.avy[j] * WV.avy[k] + WV.avz[j] * WV.avz[k];
            float cv = 0.95f * dot / (fmaxf(d1, 1e-8f) * fmaxf(d2, 1e-8f));
            float sv = sqrtf(fmaxf(1.f - cv * cv, 0.f));
            float dm = 0.5f * (d1 + d2);
            float fc2 = 2.f * WV.afc[j] * WV.afc[k];
            float pe = fmaxf(-k2 * dm * dm + __log2f(fc2), -8.0e4f);  // clamp -inf
            float pd = 2.f * k2 * dm;
            WV.pstage[lane] = make_float4(cv, sv, pd, pe);
            myrow = triu_idx(WV.asp[j], WV.asp[k]);
        }

        // in-register counting sort: 10 ballots give rank + uniform counts
        int cnt[10], st[10];
        {
            int run = 0, rank = 0, stmy = 0;
            #pragma unroll
            for (int r = 0; r < 10; ++r) {
                unsigned long long bm = __ballot(myrow == r);
                bool mine = (myrow == r);
                rank = mine ? (int)__popcll(bm & below) : rank;
                stmy = mine ? run : stmy;
                st[r]  = run;
                cnt[r] = (int)__popcll(bm);
                run += cnt[r];
            }
            if (active) WV.sortidx[stmy + rank] = lane;
        }
        WAVE_SYNC();   // sortidx/pstage visible

        // row-pair loop: half p0 processes row 2u+p0 (its own output row)
        #pragma unroll
        for (int u = 0; u < 5; ++u) {
            const int cnE = cnt[2 * u], cnO = cnt[2 * u + 1];
            const int stE = st[2 * u],  stO = st[2 * u + 1];
            const int cnMy = p0 ? cnO : cnE;
            const int stMy = p0 ? stO : stE;
            const int trips = cnE > cnO ? cnE : cnO;   // wave-uniform
            for (int o = 0; o < trips; ++o) {
                bool valid = o < cnMy;
                int idx = valid ? (stMy + o) : 0;      // safe in-bounds fallback
                int q = WV.sortidx[idx];
                float4 P = WV.pstage[q];
                // cos(theta-s) = cv*cos(s)+sv*sin(s); sv = sin(theta) >= 0
                float cd = __builtin_fmaf(P.x, myCz, P.y * mySz);
                float x = __builtin_fmaf(0.5f, cd, 0.5f);
                float f1;
                if (z32) { float x2 = x*x, x4 = x2*x2, x8 = x4*x4, x16 = x8*x8; f1 = x16*x16; }
                else     { f1 = __powf(x, zeta); }
                float term = f1 * __builtin_amdgcn_exp2f(
                                 __builtin_fmaf(P.z, myShfA, P.w - myLc));
                accs[u] += valid ? term : 0.f;
            }
        }
        WAVE_SYNC();   // WAR: drain reads before next chunk overwrites stage
    }

    // lane's 5 slots: flat angular index (2u+p0)*32 + myA*8 + myZ = 64u + lane
    #pragma unroll
    for (int u = 0; u < 5; ++u)
        stF(out, ob + RADLEN + 64 * u + lane, accs[u]);
}

__global__ __launch_bounds__(384) void aev_kernel(
    const void* coords, const void* etaR, const void* shfR, const void* etaA,
    const void* zeta, const void* shfA, const void* shfZ,
    const int* __restrict__ species, void* out)
{
    __shared__ WaveMem wm[WPB];
    // dtype probe: ShfR[0] read as f32 is 0.9 iff inputs are f32 (wave-uniform)
    const float probe = __uint_as_float(((const unsigned int*)shfR)[0]);
    if (probe > 0.85f && probe < 0.95f) {
        aev_body<float>(wm, (const float*)coords, (const float*)etaR,
                        (const float*)shfR, (const float*)etaA, (const float*)zeta,
                        (const float*)shfA, (const float*)shfZ, species, (float*)out);
    } else {
        aev_body<__hip_bfloat16>(wm, (const __hip_bfloat16*)coords,
                        (const __hip_bfloat16*)etaR, (const __hip_bfloat16*)shfR,
                        (const __hip_bfloat16*)etaA, (const __hip_bfloat16*)zeta,
                        (const __hip_bfloat16*)shfA, (const __hip_bfloat16*)shfZ,
                        species, (__hip_bfloat16*)out);
    }
}

extern "C" void kernel_launch(void* const* d_in, const int* in_sizes, int n_in,
                              void* d_out, int out_size, void* d_ws, size_t ws_size,
                              hipStream_t stream) {
    aev_kernel<<<dim3(32 * BPM), dim3(64 * WPB), 0, stream>>>(
        d_in[0], d_in[1], d_in[2], d_in[3], d_in[4], d_in[5], d_in[6],
        (const int*)d_in[7], d_out);
}

// Round 3
// 79.793 us; speedup vs baseline: 1.1686x; 1.1686x over previous
//
#include <hip/hip_runtime.h>
#include <hip/hip_bf16.h>

// AEV for M=32 molecules, A=48 atoms, S=4 species.
// Output [M, A, 384]: [0:64] radial = species*16+shfR; [64:384] angular =
// pair_species_idx*32 + shfA*8 + shfZ.
//
// HYBRID: round-0 parallel shape (1536 blocks x 4 waves per (molecule,center),
// 24 waves/CU) + round-2 wave-private angular path.
//  - All 4 waves redundantly compute neighbor distances/ballots in registers
//    (identical results); wave 0 writes the folded radial list, wave 1 writes
//    the angular list (build transcendentals split across waves).
//  - Radial: folded single-exp2, neighbors strided across waves (i = w..nR:4).
//  - Angular: wave w stages pair sub-chunks [64w, 64w+64) step 256 into its
//    PRIVATE pstage/sortidx region; species-row rank/counts via 10 ballots
//    (in-register counting sort, no LDS bins/atomics/scan). Row-pair loop
//    u=0..4: half-wave p0 owns row 2u+p0 (its natural output row). Only
//    intra-wave lgkmcnt waits per chunk -- NO block barrier in the chunk loop.
//  - Exactly 3 __syncthreads total; per-wave partials tree-reduced at the end.
//
// Dtype probed at runtime (ShfR[0] as f32 == 0.9 <=> f32 inputs).

#define NA 48
#define RCR_F 5.2f
#define RCA_F 3.5f
#define PI_F 3.14159265358979f
#define LOG2E_F 1.44269504088896f
#define RADLEN 64
#define AEVLEN 384

// Wave-local LDS drain: order prior ds_write/ds_read before subsequent ones.
// "memory" clobber blocks IR-level reordering; sched_barrier(0) blocks the
// backend scheduler from hoisting dependent ops above the wait (guide rule #18).
#define WAVE_SYNC() do { asm volatile("s_waitcnt lgkmcnt(0)" ::: "memory"); \
                         __builtin_amdgcn_sched_barrier(0); } while (0)

struct Smem {
    float sx[NA], sy[NA], sz[NA];
    int   ssp[NA];
    float ra[NA]; unsigned rbu[NA];                                // radial folded
    float ad[NA], avx[NA], avy[NA], avz[NA], afc[NA]; int asp[NA]; // d<=RCA list
    float4 pstage[4][64];   // per-wave staged pairs {cv, sv, pd, pe}
    int    sortidx[4][64];  // per-wave row-sorted pair indices
    float rpart[4][64];     // per-wave radial partials
    float apart[4][320];    // per-wave angular partials
};

template <typename T> __device__ __forceinline__ float toF(const T* p, int i);
template <> __device__ __forceinline__ float toF<float>(const float* p, int i) { return p[i]; }
template <> __device__ __forceinline__ float toF<__hip_bfloat16>(const __hip_bfloat16* p, int i) { return __bfloat162float(p[i]); }

template <typename T> __device__ __forceinline__ void stF(T* p, size_t i, float v);
template <> __device__ __forceinline__ void stF<float>(float* p, size_t i, float v) { p[i] = v; }
template <> __device__ __forceinline__ void stF<__hip_bfloat16>(__hip_bfloat16* p, size_t i, float v) { p[i] = __float2bfloat16(v); }

__device__ __forceinline__ int triu_idx(int a, int b) {
    int lo = a < b ? a : b;
    int hi = a < b ? b : a;
    return lo * 4 - (lo * (lo - 1)) / 2 + (hi - lo);  // 4x4 upper-tri, 0..9
}

template <typename T>
__device__ void aev_body(Smem& sm,
    const T* __restrict__ coords, const T* __restrict__ etaR_p,
    const T* __restrict__ shfR_p, const T* __restrict__ etaA_p,
    const T* __restrict__ zeta_p, const T* __restrict__ shfA_p,
    const T* __restrict__ shfZ_p, const int* __restrict__ species,
    T* __restrict__ out)
{
    const int tid  = threadIdx.x;   // 0..255
    const int lane = tid & 63;
    const int w    = tid >> 6;      // wave id 0..3
    const int bid  = blockIdx.x;    // 0..1535
    const int m  = bid / NA;
    const int ci = bid % NA;

    const float etaR = toF(etaR_p, 0);
    const float etaA = toF(etaA_p, 0);
    const float zeta = toF(zeta_p, 0);
    const float kR   = etaR * LOG2E_F;
    const float k2   = etaA * LOG2E_F;

    if (tid < NA) {
        int g = m * NA + tid;
        sm.sx[tid]  = toF(coords, 3 * g + 0);
        sm.sy[tid]  = toF(coords, 3 * g + 1);
        sm.sz[tid]  = toF(coords, 3 * g + 2);
        sm.ssp[tid] = species[g];
    }
    __syncthreads();   // (1) coords visible

    // ---- neighbor build: ALL waves compute identical geometry; wave 0
    //      writes the radial list, wave 1 the angular list ----
    const float cx = sm.sx[ci], cy = sm.sy[ci], cz = sm.sz[ci];
    float dx = 0.f, dy = 0.f, dz = 0.f, d = 1e30f;
    if (lane < NA && lane != ci) {
        dx = sm.sx[lane] - cx; dy = sm.sy[lane] - cy; dz = sm.sz[lane] - cz;
        d = sqrtf(dx * dx + dy * dy + dz * dz);
    }
    const unsigned long long mRm = __ballot(d <= RCR_F);
    const unsigned long long mAm = __ballot(d <= RCA_F);
    const unsigned long long lanebit = 1ull << lane;
    const unsigned long long below = lanebit - 1ull;
    if (w == 0 && (mRm & lanebit)) {
        int s = __popcll(mRm & below);
        float fcR = 0.5f * __cosf(d * (PI_F / RCR_F)) + 0.5f;
        // 0.25*exp(-etaR*(d-s)^2)*fc = exp2(ra*s + rb - kR*s^2)
        float rb = fmaxf(__log2f(0.25f * fcR) - kR * d * d, -8.0e4f);
        sm.ra[s]  = 2.f * kR * d;
        sm.rbu[s] = (__float_as_uint(rb) & ~3u) | (unsigned)sm.ssp[lane];
    }
    if (w == 1 && (mAm & lanebit)) {
        int s = __popcll(mAm & below);
        sm.ad[s]  = d;
        sm.avx[s] = dx; sm.avy[s] = dy; sm.avz[s] = dz;
        sm.afc[s] = 0.5f * __cosf(d * (PI_F / RCA_F)) + 0.5f;
        sm.asp[s] = sm.ssp[lane];
    }
    const int nR  = (int)__popcll(mRm);   // wave-uniform, identical all waves
    const int nAn = (int)__popcll(mAm);
    __syncthreads();   // (2) lists visible

    // ---- radial: lane = sp*16 + shfR_idx; neighbors strided across waves ----
    const float myShfR = toF(shfR_p, lane & 15);
    const int   mySp   = lane >> 4;
    const float myRc   = kR * myShfR * myShfR;
    float racc = 0.f;
    for (int i = w; i < nR; i += 4) {
        unsigned ru = sm.rbu[i];
        float arg = __builtin_fmaf(sm.ra[i], myShfR, __uint_as_float(ru)) - myRc;
        float t = __builtin_amdgcn_exp2f(arg);
        racc += ((int)(ru & 3u) == mySp) ? t : 0.f;
    }
    sm.rpart[w][lane] = racc;

    // ---- angular: wave-private chunks, in-register counting sort ----
    const int myA = (lane >> 3) & 3;
    const int myZ = lane & 7;
    const int p0  = lane >> 5;    // half-wave: owns rows 2u+p0
    const float myShfA = toF(shfA_p, myA);
    const float myShfZ = toF(shfZ_p, myZ);
    const float myCz = __cosf(myShfZ);
    const float mySz = __sinf(myShfZ);
    const float myLc = k2 * myShfA * myShfA;
    const bool  z32  = (zeta == 32.f);

    float accs[5] = {0.f, 0.f, 0.f, 0.f, 0.f};
    const int np = nAn * (nAn - 1) / 2;

    for (int base = 64 * w; base < np; base += 256) {
        const int nc = (np - base < 64) ? (np - base) : 64;
        const bool active = lane < nc;
        int myrow = -1;
        if (active) {
            int p = base + lane;
            // decode p -> (j,k), j<k: T(j) = j*(b-j)/2, b = 2n-1
            const int b = 2 * nAn - 1;
            float sq = sqrtf((float)(b * b - 8 * p));
            int j = (int)(((float)b - sq) * 0.5f);
            if ((j + 1) * (b - 1 - j) <= 2 * p) j++;
            if (j * (b - j) > 2 * p) j--;
            int k = p - ((j * (b - j)) >> 1) + j + 1;

            float d1 = sm.ad[j], d2 = sm.ad[k];
            float dot = sm.avx[j] * sm.avx[k] + sm.avy[j] * sm.avy[k] + sm.avz[j] * sm.avz[k];
            float cv = 0.95f * dot / (fmaxf(d1, 1e-8f) * fmaxf(d2, 1e-8f));
            float sv = sqrtf(fmaxf(1.f - cv * cv, 0.f));
            float dm = 0.5f * (d1 + d2);
            float fc2 = 2.f * sm.afc[j] * sm.afc[k];
            float pe = fmaxf(-k2 * dm * dm + __log2f(fc2), -8.0e4f);  // clamp -inf
            float pd = 2.f * k2 * dm;
            sm.pstage[w][lane] = make_float4(cv, sv, pd, pe);
            myrow = triu_idx(sm.asp[j], sm.asp[k]);
        }

        // in-register counting sort: 10 ballots give rank + uniform counts
        int cnt[10], st[10];
        {
            int run = 0, rank = 0, stmy = 0;
            #pragma unroll
            for (int r = 0; r < 10; ++r) {
                unsigned long long bm = __ballot(myrow == r);
                bool mine = (myrow == r);
                rank = mine ? (int)__popcll(bm & below) : rank;
                stmy = mine ? run : stmy;
                st[r]  = run;
                cnt[r] = (int)__popcll(bm);
                run += cnt[r];
            }
            if (active) sm.sortidx[w][stmy + rank] = lane;
        }
        WAVE_SYNC();   // this wave's pstage/sortidx visible to itself

        // row-pair loop: half p0 processes row 2u+p0 (its own output row)
        #pragma unroll
        for (int u = 0; u < 5; ++u) {
            const int cnE = cnt[2 * u], cnO = cnt[2 * u + 1];
            const int stE = st[2 * u],  stO = st[2 * u + 1];
            const int cnMy = p0 ? cnO : cnE;
            const int stMy = p0 ? stO : stE;
            const int trips = cnE > cnO ? cnE : cnO;   // wave-uniform
            for (int o = 0; o < trips; ++o) {
                bool valid = o < cnMy;
                int idx = valid ? (stMy + o) : 0;      // safe in-bounds fallback
                int q = sm.sortidx[w][idx];
                float4 P = sm.pstage[w][q];
                // cos(theta-s) = cv*cos(s)+sv*sin(s); sv = sin(theta) >= 0
                float cd = __builtin_fmaf(P.x, myCz, P.y * mySz);
                float x = __builtin_fmaf(0.5f, cd, 0.5f);
                float f1;
                if (z32) { float x2 = x*x, x4 = x2*x2, x8 = x4*x4, x16 = x8*x8; f1 = x16*x16; }
                else     { f1 = __powf(x, zeta); }
                float term = f1 * __builtin_amdgcn_exp2f(
                                 __builtin_fmaf(P.z, myShfA, P.w - myLc));
                accs[u] += valid ? term : 0.f;
            }
        }
        WAVE_SYNC();   // WAR: drain reads before next chunk overwrites stage
    }

    // lane's 5 slots: flat angular index (2u+p0)*32 + myA*8 + myZ = 64u + lane
    sm.apart[w][lane + 0]   = accs[0];
    sm.apart[w][lane + 64]  = accs[1];
    sm.apart[w][lane + 128] = accs[2];
    sm.apart[w][lane + 192] = accs[3];
    sm.apart[w][lane + 256] = accs[4];
    __syncthreads();   // (3) partials visible

    // ---- reduce partials + writeback ----
    const size_t ob = (size_t)bid * AEVLEN;
    if (tid < 64) {
        float r = sm.rpart[0][tid] + sm.rpart[1][tid] + sm.rpart[2][tid] + sm.rpart[3][tid];
        stF(out, ob + tid, r);
    }
    {
        float v = sm.apart[0][tid] + sm.apart[1][tid] + sm.apart[2][tid] + sm.apart[3][tid];
        stF(out, ob + RADLEN + tid, v);
    }
    if (tid < 64) {
        int s = 256 + tid;
        float v = sm.apart[0][s] + sm.apart[1][s] + sm.apart[2][s] + sm.apart[3][s];
        stF(out, ob + RADLEN + s, v);
    }
}

__global__ __launch_bounds__(256) void aev_kernel(
    const void* coords, const void* etaR, const void* shfR, const void* etaA,
    const void* zeta, const void* shfA, const void* shfZ,
    const int* __restrict__ species, void* out)
{
    __shared__ Smem sm;
    // dtype probe: ShfR[0] read as f32 is 0.9 iff inputs are f32 (wave-uniform)
    const float probe = __uint_as_float(((const unsigned int*)shfR)[0]);
    if (probe > 0.85f && probe < 0.95f) {
        aev_body<float>(sm, (const float*)coords, (const float*)etaR,
                        (const float*)shfR, (const float*)etaA, (const float*)zeta,
                        (const float*)shfA, (const float*)shfZ, species, (float*)out);
    } else {
        aev_body<__hip_bfloat16>(sm, (const __hip_bfloat16*)coords,
                        (const __hip_bfloat16*)etaR, (const __hip_bfloat16*)shfR,
                        (const __hip_bfloat16*)etaA, (const __hip_bfloat16*)zeta,
                        (const __hip_bfloat16*)shfA, (const __hip_bfloat16*)shfZ,
                        species, (__hip_bfloat16*)out);
    }
}

extern "C" void kernel_launch(void* const* d_in, const int* in_sizes, int n_in,
                              void* d_out, int out_size, void* d_ws, size_t ws_size,
                              hipStream_t stream) {
    aev_kernel<<<dim3(32 * NA), dim3(256), 0, stream>>>(
        d_in[0], d_in[1], d_in[2], d_in[3], d_in[4], d_in[5], d_in[6],
        (const int*)d_in[7], d_out);
}

// Round 6
// 75.164 us; speedup vs baseline: 1.2406x; 1.0616x over previous
//
#include <hip/hip_runtime.h>
#include <hip/hip_bf16.h>

// AEV for M=32 molecules, A=48 atoms, S=4 species.
// Output [M, A, 384]: [0:64] radial = species*16+shfR; [64:384] angular =
// pair_species_idx*32 + shfA*8 + shfZ.
//
// 1536 blocks x 4 waves per (molecule, center), 2 __syncthreads total.
//  - Every wave loads coords/species per-lane into registers (redundant,
//    L2-hit); wave 0 writes the packed radial list (float2), wave 1 the packed
//    angular list (float4 + float2). One barrier -> lists visible.
//  - Radial: folded single-exp2, neighbors strided across waves (i=w..nR:4),
//    one ds_read_b64 per iteration.
//  - Angular: pairs assigned MOD-4 ACROSS WAVES (p = 256c + 4*lane + w) so
//    all waves get ~np/4 pairs regardless of np (r3 gave waves 2,3 zero work).
//    Species-row rank/counts via 10 ballots (in-register counting sort);
//    PHYSICAL sort: staged float4{cv,sv,pd,pe} scatter-written to
//    pstage[st+rank], so the inner loop is ONE ds_read_b128 (no sortidx
//    indirection chain). Row-pair loop u=0..4: half-wave p0 owns row 2u+p0
//    (its natural output row). Intra-wave lgkmcnt waits only.
//  - Per-wave partials in LDS; barrier; tree-reduce + store.
//
// De-risked vs r4: plain __launch_bounds__(256) (no min-wave constraint),
// sqrtf + division instead of __builtin_amdgcn_{sqrtf,rcpf} (the exact
// arithmetic forms verified in r3) -- two container failures in a row made
// every never-executed construct suspect.
//
// Dtype probed at runtime (ShfR[0] as f32 == 0.9 <=> f32 inputs).

#define NA 48
#define RCR_F 5.2f
#define RCA_F 3.5f
#define PI_F 3.14159265358979f
#define LOG2E_F 1.44269504088896f
#define RADLEN 64
#define AEVLEN 384

// Wave-local LDS drain: order prior ds ops before subsequent ones.
// "memory" clobber blocks IR-level reordering; sched_barrier(0) blocks the
// backend scheduler from hoisting dependent ops above the wait (guide rule #18).
#define WAVE_SYNC() do { asm volatile("s_waitcnt lgkmcnt(0)" ::: "memory"); \
                         __builtin_amdgcn_sched_barrier(0); } while (0)

struct Smem {
    float2 rr[NA];          // radial: (2*kR*d, bits(rb)|species)
    float4 aj[NA];          // angular: (dx, dy, dz, d)
    float2 af[NA];          // (fc, bits(species))
    float4 pstage[4][64];   // per-wave ROW-SORTED pairs {cv, sv, pd, pe}
    float  rpart[4][64];    // per-wave radial partials
    float  apart[4][320];   // per-wave angular partials
};

template <typename T> __device__ __forceinline__ float toF(const T* p, int i);
template <> __device__ __forceinline__ float toF<float>(const float* p, int i) { return p[i]; }
template <> __device__ __forceinline__ float toF<__hip_bfloat16>(const __hip_bfloat16* p, int i) { return __bfloat162float(p[i]); }

template <typename T> __device__ __forceinline__ void stF(T* p, size_t i, float v);
template <> __device__ __forceinline__ void stF<float>(float* p, size_t i, float v) { p[i] = v; }
template <> __device__ __forceinline__ void stF<__hip_bfloat16>(__hip_bfloat16* p, size_t i, float v) { p[i] = __float2bfloat16(v); }

__device__ __forceinline__ int triu_idx(int a, int b) {
    int lo = a < b ? a : b;
    int hi = a < b ? b : a;
    return lo * 4 - (lo * (lo - 1)) / 2 + (hi - lo);  // 4x4 upper-tri, 0..9
}

template <typename T>
__device__ void aev_body(Smem& sm,
    const T* __restrict__ coords, const T* __restrict__ etaR_p,
    const T* __restrict__ shfR_p, const T* __restrict__ etaA_p,
    const T* __restrict__ zeta_p, const T* __restrict__ shfA_p,
    const T* __restrict__ shfZ_p, const int* __restrict__ species,
    T* __restrict__ out)
{
    const int tid  = threadIdx.x;   // 0..255
    const int lane = tid & 63;
    const int w    = tid >> 6;      // wave id 0..3
    const int bid  = blockIdx.x;    // 0..1535
    const int m  = bid / NA;
    const int ci = bid % NA;

    const float etaR = toF(etaR_p, 0);
    const float etaA = toF(etaA_p, 0);
    const float zeta = toF(zeta_p, 0);
    const float kR   = etaR * LOG2E_F;
    const float k2   = etaA * LOG2E_F;

    // ---- per-lane atom coords in registers (lane i <-> atom i); all waves ----
    float ax = 0.f, ay = 0.f, az = 0.f; int aspec = 0;
    if (lane < NA) {
        int g = m * NA + lane;
        ax = toF(coords, 3 * g + 0);
        ay = toF(coords, 3 * g + 1);
        az = toF(coords, 3 * g + 2);
        aspec = species[g];
    }
    const float cx = __shfl(ax, ci);
    const float cy = __shfl(ay, ci);
    const float cz = __shfl(az, ci);

    // ---- neighbor build: all waves compute geometry; w0 writes radial list,
    //      w1 writes angular list ----
    float dx = 0.f, dy = 0.f, dz = 0.f, d = 1e30f;
    if (lane < NA && lane != ci) {
        dx = ax - cx; dy = ay - cy; dz = az - cz;
        d = sqrtf(dx * dx + dy * dy + dz * dz);
    }
    const unsigned long long mRm = __ballot(d <= RCR_F);
    const unsigned long long mAm = __ballot(d <= RCA_F);
    const unsigned long long lanebit = 1ull << lane;
    const unsigned long long below = lanebit - 1ull;
    if (w == 0 && (mRm & lanebit)) {
        int s = __popcll(mRm & below);
        float fcR = 0.5f * __cosf(d * (PI_F / RCR_F)) + 0.5f;
        // 0.25*exp(-etaR*(d-s)^2)*fc = exp2(ra*s + rb - kR*s^2)
        float rb = fmaxf(__log2f(0.25f * fcR) - kR * d * d, -8.0e4f);
        unsigned ru = (__float_as_uint(rb) & ~3u) | (unsigned)aspec;
        sm.rr[s] = make_float2(2.f * kR * d, __uint_as_float(ru));
    }
    if (w == 1 && (mAm & lanebit)) {
        int s = __popcll(mAm & below);
        sm.aj[s] = make_float4(dx, dy, dz, d);
        float fcA = 0.5f * __cosf(d * (PI_F / RCA_F)) + 0.5f;
        sm.af[s] = make_float2(fcA, __uint_as_float((unsigned)aspec));
    }
    const int nR  = (int)__popcll(mRm);   // wave-uniform, identical all waves
    const int nAn = (int)__popcll(mAm);
    __syncthreads();   // (1) lists visible

    // ---- radial: lane = sp*16 + shfR_idx; neighbors strided across waves ----
    const float myShfR = toF(shfR_p, lane & 15);
    const int   mySp   = lane >> 4;
    const float myRc   = kR * myShfR * myShfR;
    float racc = 0.f;
    for (int i = w; i < nR; i += 4) {
        float2 rv = sm.rr[i];
        float arg = __builtin_fmaf(rv.x, myShfR, rv.y) - myRc;
        float t = __builtin_amdgcn_exp2f(arg);
        racc += ((int)(__float_as_uint(rv.y) & 3u) == mySp) ? t : 0.f;
    }
    sm.rpart[w][lane] = racc;

    // ---- angular: mod-4 striped pairs, physical in-register counting sort ----
    const int myA = (lane >> 3) & 3;
    const int myZ = lane & 7;
    const int p0  = lane >> 5;    // half-wave: owns rows 2u+p0
    const float myShfA = toF(shfA_p, myA);
    const float myShfZ = toF(shfZ_p, myZ);
    const float myCz = __cosf(myShfZ);
    const float mySz = __sinf(myShfZ);
    const float myLc = k2 * myShfA * myShfA;
    const bool  z32  = (zeta == 32.f);

    float accs[5] = {0.f, 0.f, 0.f, 0.f, 0.f};
    const int np = nAn * (nAn - 1) / 2;

    for (int base = 0; base < np; base += 256) {
        const int p = base + 4 * lane + w;     // wave w gets p == w (mod 4)
        const bool active = p < np;
        int myrow = -1;
        float cv = 0.f, sv = 0.f, pd = 0.f, pe = 0.f;
        if (active) {
            // decode p -> (j,k), j<k: T(j) = j*(b-j)/2, b = 2n-1
            const int b = 2 * nAn - 1;
            float sq = sqrtf((float)(b * b - 8 * p));
            int j = (int)(((float)b - sq) * 0.5f);
            if ((j + 1) * (b - 1 - j) <= 2 * p) j++;
            if (j * (b - j) > 2 * p) j--;
            int k = p - ((j * (b - j)) >> 1) + j + 1;

            float4 J = sm.aj[j], K = sm.aj[k];
            float2 Jf = sm.af[j], Kf = sm.af[k];
            float d1 = J.w, d2 = K.w;
            float dot = J.x * K.x + J.y * K.y + J.z * K.z;
            cv = 0.95f * dot / (fmaxf(d1, 1e-8f) * fmaxf(d2, 1e-8f));
            sv = sqrtf(fmaxf(1.f - cv * cv, 0.f));
            float dm = 0.5f * (d1 + d2);
            float fc2 = 2.f * Jf.x * Kf.x;
            pe = fmaxf(-k2 * dm * dm + __log2f(fc2), -8.0e4f);  // clamp -inf
            pd = 2.f * k2 * dm;
            myrow = triu_idx((int)__float_as_uint(Jf.y), (int)__float_as_uint(Kf.y));
        }

        // in-register counting sort: 10 ballots give rank + uniform counts;
        // PHYSICAL sort: scatter the float4 straight to its sorted slot.
        int cnt[10], st[10];
        {
            int run = 0, rank = 0, stmy = 0;
            #pragma unroll
            for (int r = 0; r < 10; ++r) {
                unsigned long long bm = __ballot(myrow == r);
                bool mine = (myrow == r);
                rank = mine ? (int)__popcll(bm & below) : rank;
                stmy = mine ? run : stmy;
                st[r]  = run;
                cnt[r] = (int)__popcll(bm);
                run += cnt[r];
            }
            if (active) sm.pstage[w][stmy + rank] = make_float4(cv, sv, pd, pe);
        }
        WAVE_SYNC();   // this wave's pstage visible to itself

        // row-pair loop: half p0 processes row 2u+p0 (its own output row);
        // one ds_read_b128 per iteration (2 broadcast addresses/wave).
        #pragma unroll
        for (int u = 0; u < 5; ++u) {
            const int cnE = cnt[2 * u], cnO = cnt[2 * u + 1];
            const int stE = st[2 * u],  stO = st[2 * u + 1];
            const int cnMy = p0 ? cnO : cnE;
            const int stMy = p0 ? stO : stE;
            const int trips = cnE > cnO ? cnE : cnO;   // wave-uniform
            for (int o = 0; o < trips; ++o) {
                bool valid = o < cnMy;                 // uniform per half-wave
                int idx = valid ? (stMy + o) : 0;      // safe in-bounds fallback
                float4 P = sm.pstage[w][idx];
                // cos(theta-s) = cv*cos(s)+sv*sin(s); sv = sin(theta) >= 0
                float cd = __builtin_fmaf(P.x, myCz, P.y * mySz);
                float x = __builtin_fmaf(0.5f, cd, 0.5f);
                float f1;
                if (z32) { float x2 = x*x, x4 = x2*x2, x8 = x4*x4, x16 = x8*x8; f1 = x16*x16; }
                else     { f1 = __powf(x, zeta); }
                float term = f1 * __builtin_amdgcn_exp2f(
                                 __builtin_fmaf(P.z, myShfA, P.w - myLc));
                accs[u] += valid ? term : 0.f;
            }
        }
        WAVE_SYNC();   // WAR: drain reads before next chunk overwrites pstage
    }

    // lane's 5 slots: flat angular index (2u+p0)*32 + myA*8 + myZ = 64u + lane
    sm.apart[w][lane + 0]   = accs[0];
    sm.apart[w][lane + 64]  = accs[1];
    sm.apart[w][lane + 128] = accs[2];
    sm.apart[w][lane + 192] = accs[3];
    sm.apart[w][lane + 256] = accs[4];
    __syncthreads();   // (2) partials visible

    // ---- reduce partials + writeback ----
    const size_t ob = (size_t)bid * AEVLEN;
    if (tid < 64) {
        float r = sm.rpart[0][tid] + sm.rpart[1][tid] + sm.rpart[2][tid] + sm.rpart[3][tid];
        stF(out, ob + tid, r);
    }
    {
        float v = sm.apart[0][tid] + sm.apart[1][tid] + sm.apart[2][tid] + sm.apart[3][tid];
        stF(out, ob + RADLEN + tid, v);
    }
    if (tid < 64) {
        int s = 256 + tid;
        float v = sm.apart[0][s] + sm.apart[1][s] + sm.apart[2][s] + sm.apart[3][s];
        stF(out, ob + RADLEN + s, v);
    }
}

__global__ __launch_bounds__(256) void aev_kernel(
    const void* coords, const void* etaR, const void* shfR, const void* etaA,
    const void* zeta, const void* shfA, const void* shfZ,
    const int* __restrict__ species, void* out)
{
    __shared__ Smem sm;
    // dtype probe: ShfR[0] read as f32 is 0.9 iff inputs are f32 (wave-uniform)
    const float probe = __uint_as_float(((const unsigned int*)shfR)[0]);
    if (probe > 0.85f && probe < 0.95f) {
        aev_body<float>(sm, (const float*)coords, (const float*)etaR,
                        (const float*)shfR, (const float*)etaA, (const float*)zeta,
                        (const float*)shfA, (const float*)shfZ, species, (float*)out);
    } else {
        aev_body<__hip_bfloat16>(sm, (const __hip_bfloat16*)coords,
                        (const __hip_bfloat16*)etaR, (const __hip_bfloat16*)shfR,
                        (const __hip_bfloat16*)etaA, (const __hip_bfloat16*)zeta,
                        (const __hip_bfloat16*)shfA, (const __hip_bfloat16*)shfZ,
                        species, (__hip_bfloat16*)out);
    }
}

extern "C" void kernel_launch(void* const* d_in, const int* in_sizes, int n_in,
                              void* d_out, int out_size, void* d_ws, size_t ws_size,
                              hipStream_t stream) {
    aev_kernel<<<dim3(32 * NA), dim3(256), 0, stream>>>(
        d_in[0], d_in[1], d_in[2], d_in[3], d_in[4], d_in[5], d_in[6],
        (const int*)d_in[7], d_out);
}